// Round 7
// baseline (5117.361 us; speedup 1.0000x reference)
//
#include <hip/hip_runtime.h>
#include <hip/hip_bf16.h>
#include <cstdint>
#include <cstddef>

#define VOCAB 10000
#define EMB   1024
#define HID   1024
#define BATCH 32
#define SEQ   256
#define ROWS  (SEQ*BATCH)   // 8192
#define SNBLK 16            // scan workers; 64 cols each
#define PB    128           // ctrl: published-xcc base (ints)
#define FB    1024          // ctrl: step-flag base (ints), stride 64
// ctrl slice layout (2048 ints each): [0]=cas [32]=ticket [64]=dead [66]=done [67]=sink

typedef __attribute__((ext_vector_type(8))) short short8;
typedef __attribute__((ext_vector_type(4))) float f32x4;

static __device__ __forceinline__ unsigned short f2bf(float f){
  unsigned int u = __builtin_bit_cast(unsigned int, f);
  u += 0x7fffu + ((u >> 16) & 1u);
  return (unsigned short)(u >> 16);
}

// ---------- transpose-convert: fp32 src[K][N] -> bf16 dst[N][K] ----------
__global__ void k_transpose(const float* __restrict__ src, unsigned short* __restrict__ dst,
                            int K, int N){
  __shared__ unsigned short tile[64][65];
  int n0 = blockIdx.x * 64, k0 = blockIdx.y * 64;
  int tid = threadIdx.x;
  #pragma unroll
  for (int it = 0; it < 16; ++it){
    int e = tid + it*256;
    int i = e >> 6, j = e & 63;
    float v = 0.f;
    if (k0 + i < K && n0 + j < N) v = src[(size_t)(k0+i)*N + n0 + j];
    tile[j][i] = f2bf(v);
  }
  __syncthreads();
  #pragma unroll
  for (int it = 0; it < 16; ++it){
    int e = tid + it*256;
    int r = e >> 6, c = e & 63;
    if (n0 + r < N && k0 + c < K)
      dst[(size_t)(n0+r)*K + k0 + c] = tile[r][c];
  }
}

// ---------- embedding gather + fp32->bf16 ----------
__global__ void k_gather(const int* __restrict__ seq, const float* __restrict__ emb,
                         unsigned short* __restrict__ X){
  int r = blockIdx.x;                 // r = t*32 + b
  int t = r >> 5, b = r & 31;
  int idx = seq[b*SEQ + t];
  const float4* s = (const float4*)(emb + (size_t)idx * EMB);
  float4 v = s[threadIdx.x];
  ushort4 o;
  o.x = f2bf(v.x); o.y = f2bf(v.y); o.z = f2bf(v.z); o.w = f2bf(v.w);
  ((ushort4*)(X + (size_t)r * EMB))[threadIdx.x] = o;
}

// ---------- GEMM: C[M][ldc] = A[M][K](bf16) * BT[Npad][K](bf16)^T + bias ----------
template<bool OUT_BF16>
__global__ __launch_bounds__(256) void k_gemm_bt(
    const unsigned short* __restrict__ A,
    const unsigned short* __restrict__ BT,
    const float* __restrict__ bias,
    void* __restrict__ C, int M, int Nreal, int K, int ldc){
  __shared__ __align__(16) unsigned short As[128][40];
  __shared__ __align__(16) unsigned short Bs[128][40];
  int tid  = threadIdx.x;
  int lane = tid & 63, wid = tid >> 6;
  int wr = (wid >> 1) * 64, wc = (wid & 1) * 64;
  int m0 = blockIdx.y * 128, n0 = blockIdx.x * 128;
  int la = lane & 15, ko = (lane >> 4) * 8;
  f32x4 acc[4][4] = {};
  for (int k0 = 0; k0 < K; k0 += 32){
    #pragma unroll
    for (int q = tid; q < 512; q += 256){
      int row = q >> 2, kc = (q & 3) * 8;
      *(uint4*)&As[row][kc] = *(const uint4*)(A  + (size_t)(m0+row)*K + k0 + kc);
      *(uint4*)&Bs[row][kc] = *(const uint4*)(BT + (size_t)(n0+row)*K + k0 + kc);
    }
    __syncthreads();
    short8 av[4], bv[4];
    #pragma unroll
    for (int f = 0; f < 4; ++f){
      av[f] = *(const short8*)&As[wr + f*16 + la][ko];
      bv[f] = *(const short8*)&Bs[wc + f*16 + la][ko];
    }
    #pragma unroll
    for (int mf = 0; mf < 4; ++mf)
      #pragma unroll
      for (int nf = 0; nf < 4; ++nf)
        acc[mf][nf] = __builtin_amdgcn_mfma_f32_16x16x32_bf16(av[mf], bv[nf], acc[mf][nf], 0, 0, 0);
    __syncthreads();
  }
  int dr = (lane >> 4) * 4, dc = lane & 15;
  #pragma unroll
  for (int mf = 0; mf < 4; ++mf){
    #pragma unroll
    for (int nf = 0; nf < 4; ++nf){
      int col = n0 + wc + nf*16 + dc;
      if (col >= Nreal) continue;
      float bb = bias[col];
      #pragma unroll
      for (int rg = 0; rg < 4; ++rg){
        int row = m0 + wr + mf*16 + dr + rg;
        float v = acc[mf][nf][rg] + bb;
        if (OUT_BF16) ((unsigned short*)C)[(size_t)row*ldc + col] = f2bf(v);
        else          ((float*)C)[(size_t)row*ldc + col] = v;
      }
    }
  }
}

// ---------- persistent scan (MODE 0) / free-running ablation (MODE 1) ----------
// 16 elected colocated workers; non-elected blocks become anti-throttle burners
// (one block per CU via 144KB LDS) spinning FMAs until the done-flag.
template<int MODE>
__global__ __launch_bounds__(256, 1) void k_scan(
    const unsigned short* __restrict__ UT,   // [HID][HID] bf16, UT[n][k]
    const float* __restrict__ G0,            // [ROWS][HID] fp32 (includes b_gate)
    unsigned short* __restrict__ Hbase,      // MODE0: Hfull; MODE1: Hfull+32*HID
    int* ctrl){
  __shared__ __align__(16) unsigned short UTs[64*1024];  // 128 KB, swizzled
  __shared__ float red[2][32][64];                       // 16 KB
  __shared__ int s_slot, s_fast;
  const int tid  = threadIdx.x;
  const int lane = tid & 63, wid = tid >> 6;
  const int NT = MODE ? 512 : SEQ;

  // ---- election ----
  if (tid == 0){
    int xcc;
    asm volatile("s_getreg_b32 %0, hwreg(HW_REG_XCC_ID)" : "=s"(xcc));
    xcc &= 0xff;
    int expected = 0;
    __hip_atomic_compare_exchange_strong(&ctrl[0], &expected, xcc + 1,
        __ATOMIC_ACQ_REL, __ATOMIC_ACQUIRE, __HIP_MEMORY_SCOPE_AGENT);
    int lead = (expected == 0) ? xcc : expected - 1;
    int ticket = -1;
    if (xcc == lead)
      ticket = __hip_atomic_fetch_add(&ctrl[32], 1, __ATOMIC_RELAXED, __HIP_MEMORY_SCOPE_AGENT);
    int slot = (ticket >= 0 && ticket < SNBLK) ? ticket : -1;
    int fast = 1;
    if (slot >= 0){
      __hip_atomic_store(&ctrl[PB + slot], xcc + 1, __ATOMIC_RELEASE, __HIP_MEMORY_SCOPE_AGENT);
      for (int i = 0; i < SNBLK; ++i){
        int v;
        int guard = 0;
        while ((v = __hip_atomic_load(&ctrl[PB + i], __ATOMIC_ACQUIRE, __HIP_MEMORY_SCOPE_AGENT)) == 0){
          __builtin_amdgcn_s_sleep(8);
          if (++guard > 100000) break;           // leader XCD has 32 CUs; fills fast
        }
        if (v == 0 || v - 1 != xcc) fast = 0;
      }
    }
    s_slot = slot; s_fast = fast;
  }
  __syncthreads();
  const int slot = s_slot, fastp = s_fast;

  if (slot < 0){
    // ---- anti-throttle burner: dependent FMA spin until done-flag ----
    float x = (float)tid * 0.001f + 1.0f;
    const float y = 1.0000001f;
    for (int it = 0; it < 200000; ++it){          // hard cap ~10 ms
      #pragma unroll
      for (int j = 0; j < 32; ++j) x = __builtin_fmaf(x, y, 1e-7f);
      if ((it & 127) == 0 &&
          __hip_atomic_load(&ctrl[66], __ATOMIC_RELAXED, __HIP_MEMORY_SCOPE_AGENT) != 0)
        break;
    }
    if (x == 12345.678f)                          // never true; keeps chain live
      __hip_atomic_store(&ctrl[67], 1, __ATOMIC_RELAXED, __HIP_MEMORY_SCOPE_AGENT);
    return;
  }
  const int n0 = slot * 64;

  // ---- U slice -> LDS, 16B-chunk XOR swizzle ----
  for (int i = tid; i < 8192; i += 256){
    int r = i >> 7, cc = i & 127;
    uint4 v = *(const uint4*)(UT + (size_t)(n0 + r)*HID + cc*8);
    *(uint4*)&UTs[r*1024 + ((cc ^ (r & 7)) * 8)] = v;
  }
  __syncthreads();

  const int kh = wid >> 1, ch = wid & 1;
  const int la = lane & 15, kg = lane >> 4;
  const int b  = tid >> 3, nn = (tid & 7) * 8;

  const int row0 = ch*32 + la, row1 = ch*32 + 16 + la;
  const unsigned short* ub0 = UTs + row0*1024;
  const unsigned short* ub1 = UTs + row1*1024;
  const int sw0 = row0 & 7, sw1 = row1 & 7;

  float creg[8];
  #pragma unroll
  for (int j = 0; j < 8; ++j) creg[j] = 0.f;
  float g0r[8];
  {
    const float* gp = G0 + (size_t)b * HID + n0 + nn;
    float4 lo = *(const float4*)gp, hi = *(const float4*)(gp + 4);
    g0r[0]=lo.x; g0r[1]=lo.y; g0r[2]=lo.z; g0r[3]=lo.w;
    g0r[4]=hi.x; g0r[5]=hi.y; g0r[6]=hi.z; g0r[7]=hi.w;
  }

  for (int t = 0; t < NT; ++t){
    // ---- wait for peers' h_{t-1} (MODE 0 only) ----
    if (MODE == 0 && t > 0){
      const int pi = lane & 15;
      const int* fp = &ctrl[FB + pi*64];
      int guard = 0, dead = 0;
      for (;;){
        int v = (pi == slot) ? 0x7fffffff
              : __hip_atomic_load(fp, __ATOMIC_RELAXED, __HIP_MEMORY_SCOPE_AGENT);
        if (__all(v >= t)) break;
        if (++guard > (1<<15)) { dead = 1; break; }
      }
      if (dead && lane == 0)
        __hip_atomic_fetch_or(&ctrl[64], 1, __ATOMIC_RELAXED, __HIP_MEMORY_SCOPE_AGENT);
      if (!fastp) __threadfence();
    }

    // ---- h_{t-1} @ U : pipelined A-ring ----
    const int tr = MODE ? (t & 127) : t;
    const unsigned short* hp  = Hbase + (size_t)tr*32*HID + kh*512 + kg*8;
    const unsigned short* hpA = hp + (size_t)la * HID;
    const unsigned short* hpB = hp + (size_t)(16 + la) * HID;
    short8 A0r[8], A1r[8];
    #pragma unroll
    for (int i = 0; i < 8; ++i){
      A0r[i] = *(const short8*)(hpA + i*32);
      A1r[i] = *(const short8*)(hpB + i*32);
    }
    f32x4 a00 = {0,0,0,0}, a01 = {0,0,0,0}, a10 = {0,0,0,0}, a11 = {0,0,0,0};
    #pragma unroll
    for (int kc = 0; kc < 16; ++kc){
      int cidx = (kh*16 + kc)*4 + kg;
      short8 b0 = *(const short8*)(ub0 + ((cidx ^ sw0) << 3));
      short8 b1 = *(const short8*)(ub1 + ((cidx ^ sw1) << 3));
      short8 a0 = A0r[kc & 7], a1 = A1r[kc & 7];
      if (kc < 8){
        A0r[kc] = *(const short8*)(hpA + (kc + 8)*32);
        A1r[kc] = *(const short8*)(hpB + (kc + 8)*32);
      }
      a00 = __builtin_amdgcn_mfma_f32_16x16x32_bf16(a0, b0, a00, 0, 0, 0);
      a01 = __builtin_amdgcn_mfma_f32_16x16x32_bf16(a0, b1, a01, 0, 0, 0);
      a10 = __builtin_amdgcn_mfma_f32_16x16x32_bf16(a1, b0, a10, 0, 0, 0);
      a11 = __builtin_amdgcn_mfma_f32_16x16x32_bf16(a1, b1, a11, 0, 0, 0);
    }
    #pragma unroll
    for (int rg = 0; rg < 4; ++rg){
      red[kh][kg*4 + rg][ch*32 + la]           = a00[rg];
      red[kh][kg*4 + rg][ch*32 + 16 + la]      = a01[rg];
      red[kh][16 + kg*4 + rg][ch*32 + la]      = a10[rg];
      red[kh][16 + kg*4 + rg][ch*32 + 16 + la] = a11[rg];
    }
    __syncthreads();

    // ---- gates + h-write ----
    short8 hv;
    #pragma unroll
    for (int j = 0; j < 8; ++j){
      float g  = red[0][b][nn + j] + red[1][b][nn + j] + g0r[j];
      float e  = __expf(-g);
      float s  = __builtin_amdgcn_rcpf(1.f + e);
      float e2 = e * e;
      float tg = 2.f * __builtin_amdgcn_rcpf(1.f + e2) - 1.f;
      float cn = s * (creg[j] + tg);
      creg[j] = cn;
      float ec = __expf(-2.f * cn);
      float th = 2.f * __builtin_amdgcn_rcpf(1.f + ec) - 1.f;
      hv[j] = (short)f2bf(th * s);
    }
    const int tw = MODE ? ((t + 1) & 127) : (t + 1);
    *(short8*)(Hbase + ((size_t)tw*32 + b) * HID + n0 + nn) = hv;

    if (t + 1 < NT){   // G0 prefetch BEFORE barrier (its vmcnt(0) drains it)
      const int tg0 = MODE ? ((t + 1) & 255) : (t + 1);
      const float* gp = G0 + ((size_t)tg0*32 + b) * HID + n0 + nn;
      float4 lo = *(const float4*)gp, hi = *(const float4*)(gp + 4);
      g0r[0]=lo.x; g0r[1]=lo.y; g0r[2]=lo.z; g0r[3]=lo.w;
      g0r[4]=hi.x; g0r[5]=hi.y; g0r[6]=hi.z; g0r[7]=hi.w;
    }
    __syncthreads();               // all waves' h-stores drained before flag
    if (tid == 0){
      if (MODE == 0 && !fastp) __threadfence();
      __hip_atomic_store(&ctrl[FB + slot*64], t + 1, __ATOMIC_RELAXED, __HIP_MEMORY_SCOPE_AGENT);
    }
  }

  // telemetry (MODE 0): slow path +1ms, deadman +4ms
  if (MODE == 0 && slot == 0 && tid == 0){
    long long spin = 0;
    if (!fastp) spin += 100000LL;
    if (__hip_atomic_load(&ctrl[64], __ATOMIC_RELAXED, __HIP_MEMORY_SCOPE_AGENT) != 0)
      spin += 400000LL;
    if (spin){
      long long t0 = __builtin_amdgcn_s_memrealtime();
      while (__builtin_amdgcn_s_memrealtime() - t0 < spin) {}
    }
  }
  // release burners
  if (slot == 0 && tid == 0)
    __hip_atomic_store(&ctrl[66], 1, __ATOMIC_RELAXED, __HIP_MEMORY_SCOPE_AGENT);
}

extern "C" void kernel_launch(void* const* d_in, const int* in_sizes, int n_in,
                              void* d_out, int out_size, void* d_ws, size_t ws_size,
                              hipStream_t stream){
  (void)in_sizes; (void)n_in; (void)out_size;
  const int*   seq     = (const int*)d_in[0];
  const float* emb     = (const float*)d_in[1];
  const float* w_gate  = (const float*)d_in[2];
  const float* b_gate  = (const float*)d_in[3];
  const float* w_out   = (const float*)d_in[4];
  const float* b_out   = (const float*)d_in[5];
  const float* w_dense = (const float*)d_in[6];
  const float* b_dense = (const float*)d_in[7];
  float* out = (float*)d_out;

  const int NPAD_D = 10112;   // 79 * 128
  char* ws = (char*)d_ws;
  size_t off = 0;
  auto alloc = [&](size_t bytes){ size_t o = off; off += (bytes + 255) & ~(size_t)255; return o; };
  size_t off_W1T = alloc((size_t)2*HID*HID);
  size_t off_UT  = alloc((size_t)2*HID*HID);
  size_t off_WoT = alloc((size_t)2*HID*HID);
  size_t off_WdT = alloc((size_t)2*NPAD_D*HID);
  size_t off_X   = alloc((size_t)2*ROWS*EMB);             // bf16; reused as YS
  size_t off_G0  = alloc((size_t)4*ROWS*HID);
  size_t off_H   = alloc((size_t)2*(ROWS+32)*HID);
  size_t off_ctl = alloc(16384);                          // 2 ctrl slices of 2048 ints
  if (ws_size < off) return;

  unsigned short* W1T = (unsigned short*)(ws + off_W1T);
  unsigned short* UT  = (unsigned short*)(ws + off_UT);
  unsigned short* WoT = (unsigned short*)(ws + off_WoT);
  unsigned short* WdT = (unsigned short*)(ws + off_WdT);
  unsigned short* X   = (unsigned short*)(ws + off_X);
  unsigned short* YS  = (unsigned short*)(ws + off_X);
  float*          G0  = (float*)(ws + off_G0);
  unsigned short* Hf  = (unsigned short*)(ws + off_H);
  int*            ctl = (int*)(ws + off_ctl);

  hipMemsetAsync(ctl, 0, 16384, stream);
  hipMemsetAsync(WdT + (size_t)10000*HID, 0, (size_t)2*(NPAD_D-10000)*HID, stream);
  hipMemsetAsync(Hf, 0, (size_t)2*32*HID, stream);

  k_transpose<<<dim3(16,16), 256, 0, stream>>>(w_gate,           W1T, HID, HID);
  k_transpose<<<dim3(16,16), 256, 0, stream>>>(w_gate + HID*HID, UT,  HID, HID);
  k_transpose<<<dim3(16,16), 256, 0, stream>>>(w_out,            WoT, HID, HID);
  k_transpose<<<dim3(157,16),256, 0, stream>>>(w_dense,          WdT, HID, VOCAB);

  k_gather<<<ROWS, 256, 0, stream>>>(seq, emb, X);

  // G0 = X @ W1 + b_gate  (fp32 out)
  k_gemm_bt<false><<<dim3(8,64), 256, 0, stream>>>(X, W1T, b_gate, G0, ROWS, HID, EMB, HID);

  // ablation probe: free-running colocated core, 512 steps, no poll, burners on
  k_scan<1><<<256, 256, 0, stream>>>(UT, G0, Hf + (size_t)32*HID, ctl + 2048);

  // real sequential scan (burners on)
  k_scan<0><<<256, 256, 0, stream>>>(UT, G0, Hf, ctl);

  // ys = H @ w_out + b_out  (bf16 out, into X region)
  k_gemm_bt<true><<<dim3(8,64), 256, 0, stream>>>(Hf + (size_t)32*HID, WoT, b_out, YS,
                                                  ROWS, HID, HID, HID);

  // logits = ys @ w_dense + b_dense (fp32 out)
  k_gemm_bt<false><<<dim3(79,64), 256, 0, stream>>>(YS, WdT, b_dense, out,
                                                    ROWS, VOCAB, HID, VOCAB);
}

// Round 8
// 2459.598 us; speedup vs baseline: 2.0806x; 2.0806x over previous
//
#include <hip/hip_runtime.h>
#include <hip/hip_bf16.h>
#include <cstdint>
#include <cstddef>

#define VOCAB 10000
#define EMB   1024
#define HID   1024
#define BATCH 32
#define SEQ   256
#define ROWS  (SEQ*BATCH)   // 8192
#define SNBLK 16            // scan workers; 64 cols each
#define PB    128           // ctrl: published-xcc base (ints)
#define FB    1024          // ctrl: step-flag base (ints); flag[slot][wid] at FB+slot*64+wid*16

typedef __attribute__((ext_vector_type(8))) short short8;
typedef __attribute__((ext_vector_type(4))) float f32x4;

static __device__ __forceinline__ unsigned short f2bf(float f){
  unsigned int u = __builtin_bit_cast(unsigned int, f);
  u += 0x7fffu + ((u >> 16) & 1u);
  return (unsigned short)(u >> 16);
}

// ---------- transpose-convert: fp32 src[K][N] -> bf16 dst[N][K] ----------
__global__ void k_transpose(const float* __restrict__ src, unsigned short* __restrict__ dst,
                            int K, int N){
  __shared__ unsigned short tile[64][65];
  int n0 = blockIdx.x * 64, k0 = blockIdx.y * 64;
  int tid = threadIdx.x;
  #pragma unroll
  for (int it = 0; it < 16; ++it){
    int e = tid + it*256;
    int i = e >> 6, j = e & 63;
    float v = 0.f;
    if (k0 + i < K && n0 + j < N) v = src[(size_t)(k0+i)*N + n0 + j];
    tile[j][i] = f2bf(v);
  }
  __syncthreads();
  #pragma unroll
  for (int it = 0; it < 16; ++it){
    int e = tid + it*256;
    int r = e >> 6, c = e & 63;
    if (n0 + r < N && k0 + c < K)
      dst[(size_t)(n0+r)*K + k0 + c] = tile[r][c];
  }
}

// ---------- embedding gather + fp32->bf16 ----------
__global__ void k_gather(const int* __restrict__ seq, const float* __restrict__ emb,
                         unsigned short* __restrict__ X){
  int r = blockIdx.x;                 // r = t*32 + b
  int t = r >> 5, b = r & 31;
  int idx = seq[b*SEQ + t];
  const float4* s = (const float4*)(emb + (size_t)idx * EMB);
  float4 v = s[threadIdx.x];
  ushort4 o;
  o.x = f2bf(v.x); o.y = f2bf(v.y); o.z = f2bf(v.z); o.w = f2bf(v.w);
  ((ushort4*)(X + (size_t)r * EMB))[threadIdx.x] = o;
}

// ---------- GEMM: C[M][ldc] = A[M][K](bf16) * BT[Npad][K](bf16)^T + bias ----------
template<bool OUT_BF16>
__global__ __launch_bounds__(256) void k_gemm_bt(
    const unsigned short* __restrict__ A,
    const unsigned short* __restrict__ BT,
    const float* __restrict__ bias,
    void* __restrict__ C, int M, int Nreal, int K, int ldc){
  __shared__ __align__(16) unsigned short As[128][40];
  __shared__ __align__(16) unsigned short Bs[128][40];
  int tid  = threadIdx.x;
  int lane = tid & 63, wid = tid >> 6;
  int wr = (wid >> 1) * 64, wc = (wid & 1) * 64;
  int m0 = blockIdx.y * 128, n0 = blockIdx.x * 128;
  int la = lane & 15, ko = (lane >> 4) * 8;
  f32x4 acc[4][4] = {};
  for (int k0 = 0; k0 < K; k0 += 32){
    #pragma unroll
    for (int q = tid; q < 512; q += 256){
      int row = q >> 2, kc = (q & 3) * 8;
      *(uint4*)&As[row][kc] = *(const uint4*)(A  + (size_t)(m0+row)*K + k0 + kc);
      *(uint4*)&Bs[row][kc] = *(const uint4*)(BT + (size_t)(n0+row)*K + k0 + kc);
    }
    __syncthreads();
    short8 av[4], bv[4];
    #pragma unroll
    for (int f = 0; f < 4; ++f){
      av[f] = *(const short8*)&As[wr + f*16 + la][ko];
      bv[f] = *(const short8*)&Bs[wc + f*16 + la][ko];
    }
    #pragma unroll
    for (int mf = 0; mf < 4; ++mf)
      #pragma unroll
      for (int nf = 0; nf < 4; ++nf)
        acc[mf][nf] = __builtin_amdgcn_mfma_f32_16x16x32_bf16(av[mf], bv[nf], acc[mf][nf], 0, 0, 0);
    __syncthreads();
  }
  int dr = (lane >> 4) * 4, dc = lane & 15;
  #pragma unroll
  for (int mf = 0; mf < 4; ++mf){
    #pragma unroll
    for (int nf = 0; nf < 4; ++nf){
      int col = n0 + wc + nf*16 + dc;
      if (col >= Nreal) continue;
      float bb = bias[col];
      #pragma unroll
      for (int rg = 0; rg < 4; ++rg){
        int row = m0 + wr + mf*16 + dr + rg;
        float v = acc[mf][nf][rg] + bb;
        if (OUT_BF16) ((unsigned short*)C)[(size_t)row*ldc + col] = f2bf(v);
        else          ((float*)C)[(size_t)row*ldc + col] = v;
      }
    }
  }
}

// ---------- persistent scan: 16 colocated workers; reg-resident inner step ----------
// Per step per wave: 32 A-preload (global, L2) + 8-deep B-ring (LDS) -> pure-reg
// MFMA stream -> padded red -> gates. Per-wave flags; wave0-only poll.
__global__ __launch_bounds__(256, 1) void k_scan(
    const unsigned short* __restrict__ UT,   // [HID][HID] bf16, UT[n][k]
    const float* __restrict__ G0,            // [ROWS][HID] fp32 (includes b_gate)
    unsigned short* __restrict__ Hfull,      // [(32+ROWS)][HID] bf16, rows 0..31 zeroed
    int* ctrl){
  __shared__ __align__(16) unsigned short UTs[64*1024];  // 128 KB, swizzled
  __shared__ float red[2][32][68];                       // 17.4 KB, padded stride
  __shared__ int s_slot, s_fast;
  const int tid  = threadIdx.x;
  const int lane = tid & 63, wid = tid >> 6;

  // ---- election (r5/r6 variant: leader-XCD preference + timeout fallback) ----
  if (tid == 0){
    int xcc;
    asm volatile("s_getreg_b32 %0, hwreg(HW_REG_XCC_ID)" : "=s"(xcc));
    xcc &= 0xff;
    int expected = 0;
    __hip_atomic_compare_exchange_strong(&ctrl[0], &expected, xcc + 1,
        __ATOMIC_ACQ_REL, __ATOMIC_ACQUIRE, __HIP_MEMORY_SCOPE_AGENT);
    int lead = (expected == 0) ? xcc : expected - 1;
    int ticket = -1;
    if (xcc == lead){
      ticket = __hip_atomic_fetch_add(&ctrl[32], 1, __ATOMIC_RELAXED, __HIP_MEMORY_SCOPE_AGENT);
    } else {
      for (int it = 0; it < 64; ++it){
        if (__hip_atomic_load(&ctrl[32], __ATOMIC_RELAXED, __HIP_MEMORY_SCOPE_AGENT) >= SNBLK) break;
        for (int j = 0; j < 4; ++j) __builtin_amdgcn_s_sleep(32);
      }
      if (__hip_atomic_load(&ctrl[32], __ATOMIC_RELAXED, __HIP_MEMORY_SCOPE_AGENT) < SNBLK)
        ticket = __hip_atomic_fetch_add(&ctrl[32], 1, __ATOMIC_RELAXED, __HIP_MEMORY_SCOPE_AGENT);
    }
    int slot = (ticket >= 0 && ticket < SNBLK) ? ticket : -1;
    int fast = 1;
    if (slot >= 0){
      __hip_atomic_store(&ctrl[PB + slot], xcc + 1, __ATOMIC_RELEASE, __HIP_MEMORY_SCOPE_AGENT);
      for (int i = 0; i < SNBLK; ++i){
        int v;
        while ((v = __hip_atomic_load(&ctrl[PB + i], __ATOMIC_ACQUIRE, __HIP_MEMORY_SCOPE_AGENT)) == 0)
          __builtin_amdgcn_s_sleep(8);
        if (v - 1 != xcc) fast = 0;
      }
    }
    s_slot = slot; s_fast = fast;
  }
  __syncthreads();
  const int slot = s_slot, fastp = s_fast;
  if (slot < 0) return;
  const int n0 = slot * 64;

  // ---- U slice -> LDS, 16B-chunk XOR swizzle ----
  for (int i = tid; i < 8192; i += 256){
    int r = i >> 7, cc = i & 127;
    uint4 v = *(const uint4*)(UT + (size_t)(n0 + r)*HID + cc*8);
    *(uint4*)&UTs[r*1024 + ((cc ^ (r & 7)) * 8)] = v;
  }
  __syncthreads();

  const int kh = wid >> 1, ch = wid & 1;     // wave = (K-half, col-half)
  const int la = lane & 15, kg = lane >> 4;
  const int b  = tid >> 3, nn = (tid & 7) * 8;

  const int row0 = ch*32 + la, row1 = row0 + 16;
  const unsigned short* ub0 = UTs + row0*1024;
  const unsigned short* ub1 = UTs + row1*1024;
  const int sw0 = row0 & 7, sw1 = row1 & 7;

  float creg[8];
  #pragma unroll
  for (int j = 0; j < 8; ++j) creg[j] = 0.f;
  float g0r[8];
  {
    const float* gp = G0 + (size_t)b * HID + n0 + nn;
    float4 lo = *(const float4*)gp, hi = *(const float4*)(gp + 4);
    g0r[0]=lo.x; g0r[1]=lo.y; g0r[2]=lo.z; g0r[3]=lo.w;
    g0r[4]=hi.x; g0r[5]=hi.y; g0r[6]=hi.z; g0r[7]=hi.w;
  }

  for (int t = 0; t < SEQ; ++t){
    // ---- wave0 polls all 16 slots x 4 wave-flags; others wait at the barrier ----
    if (t > 0){
      if (wid == 0){
        const int* fp = &ctrl[FB + (lane & 15)*64 + (lane >> 4)*16];
        int guard = 0, dead = 0;
        for (;;){
          int v = __hip_atomic_load(fp, __ATOMIC_RELAXED, __HIP_MEMORY_SCOPE_AGENT);
          if (__all(v >= t)) break;
          if (++guard > (1<<15)) { dead = 1; break; }
        }
        if (dead && lane == 0)
          __hip_atomic_fetch_or(&ctrl[64], 1, __ATOMIC_RELAXED, __HIP_MEMORY_SCOPE_AGENT);
        if (!fastp) __threadfence();     // slow path: inv before remote h-reads
      }
      __syncthreads();                   // sync(a): also orders gates@t-1 vs red@t
    }

    // ---- G0 prefetch for NEXT step, issued first (HBM latency hides under step) ----
    float4 gnlo, gnhi;
    {
      int tn = (t + 1 < SEQ) ? (t + 1) : t;
      const float* gp = G0 + ((size_t)tn*32 + b) * HID + n0 + nn;
      gnlo = *(const float4*)gp; gnhi = *(const float4*)(gp + 4);
    }

    // ---- full A preload: 32 x b128 per lane (L2) ----
    const unsigned short* hp  = Hfull + (size_t)t*32*HID + kh*512 + kg*8;
    const unsigned short* hpA = hp + (size_t)la * HID;
    const unsigned short* hpB = hp + (size_t)(16 + la) * HID;
    short8 A0r[16], A1r[16];
    #pragma unroll
    for (int i = 0; i < 16; ++i){
      A0r[i] = *(const short8*)(hpA + i*32);
      A1r[i] = *(const short8*)(hpB + i*32);
    }

    // ---- B ring: preload 8, refill 8 in-loop (LDS latency fully covered) ----
    short8 B0r[8], B1r[8];
    #pragma unroll
    for (int kc = 0; kc < 8; ++kc){
      int cidx = (kh*16 + kc)*4 + kg;
      B0r[kc] = *(const short8*)(ub0 + ((cidx ^ sw0) << 3));
      B1r[kc] = *(const short8*)(ub1 + ((cidx ^ sw1) << 3));
    }

    f32x4 a00 = {0,0,0,0}, a01 = {0,0,0,0}, a10 = {0,0,0,0}, a11 = {0,0,0,0};
    #pragma unroll
    for (int kc = 0; kc < 16; ++kc){
      short8 b0 = B0r[kc & 7], b1 = B1r[kc & 7];
      if (kc < 8){
        int cidx = (kh*16 + kc + 8)*4 + kg;
        B0r[kc] = *(const short8*)(ub0 + ((cidx ^ sw0) << 3));
        B1r[kc] = *(const short8*)(ub1 + ((cidx ^ sw1) << 3));
      }
      a00 = __builtin_amdgcn_mfma_f32_16x16x32_bf16(A0r[kc], b0, a00, 0, 0, 0);
      a01 = __builtin_amdgcn_mfma_f32_16x16x32_bf16(A0r[kc], b1, a01, 0, 0, 0);
      a10 = __builtin_amdgcn_mfma_f32_16x16x32_bf16(A1r[kc], b0, a10, 0, 0, 0);
      a11 = __builtin_amdgcn_mfma_f32_16x16x32_bf16(A1r[kc], b1, a11, 0, 0, 0);
    }
    #pragma unroll
    for (int rg = 0; rg < 4; ++rg){
      red[kh][kg*4 + rg][ch*32 + la]           = a00[rg];
      red[kh][kg*4 + rg][ch*32 + 16 + la]      = a01[rg];
      red[kh][16 + kg*4 + rg][ch*32 + la]      = a10[rg];
      red[kh][16 + kg*4 + rg][ch*32 + 16 + la] = a11[rg];
    }
    __syncthreads();                     // sync(b): red complete

    // ---- gates: vector red reads (padded, ~2-way banks) + fast tanh ----
    float4 r0lo = *(const float4*)&red[0][b][nn];
    float4 r0hi = *(const float4*)&red[0][b][nn + 4];
    float4 r1lo = *(const float4*)&red[1][b][nn];
    float4 r1hi = *(const float4*)&red[1][b][nn + 4];
    float gg[8] = { r0lo.x + r1lo.x + g0r[0], r0lo.y + r1lo.y + g0r[1],
                    r0lo.z + r1lo.z + g0r[2], r0lo.w + r1lo.w + g0r[3],
                    r0hi.x + r1hi.x + g0r[4], r0hi.y + r1hi.y + g0r[5],
                    r0hi.z + r1hi.z + g0r[6], r0hi.w + r1hi.w + g0r[7] };
    short8 hv;
    #pragma unroll
    for (int j = 0; j < 8; ++j){
      float g  = gg[j];
      float e  = __expf(-g);
      float s  = __builtin_amdgcn_rcpf(1.f + e);
      float e2 = e * e;
      float tg = 2.f * __builtin_amdgcn_rcpf(1.f + e2) - 1.f;
      float cn = s * (creg[j] + tg);
      creg[j] = cn;
      float ec = __expf(-2.f * cn);
      float th = 2.f * __builtin_amdgcn_rcpf(1.f + ec) - 1.f;
      hv[j] = (short)f2bf(th * s);
    }
    *(short8*)(Hfull + ((size_t)(t+1)*32 + b) * HID + n0 + nn) = hv;

    // ---- per-wave flag: own stores drained -> publish ----
    asm volatile("s_waitcnt vmcnt(0)" ::: "memory");   // also drains gnlo/gnhi loads
    if (!fastp) __threadfence();
    if (lane == 0)
      __hip_atomic_store(&ctrl[FB + slot*64 + wid*16], t + 1,
                         __ATOMIC_RELAXED, __HIP_MEMORY_SCOPE_AGENT);

    g0r[0]=gnlo.x; g0r[1]=gnlo.y; g0r[2]=gnlo.z; g0r[3]=gnlo.w;
    g0r[4]=gnhi.x; g0r[5]=gnhi.y; g0r[6]=gnhi.z; g0r[7]=gnhi.w;
  }

  // telemetry: slow path +1ms, any deadman +4ms
  if (slot == 0 && tid == 0){
    long long spin = 0;
    if (!fastp) spin += 100000LL;
    if (__hip_atomic_load(&ctrl[64], __ATOMIC_RELAXED, __HIP_MEMORY_SCOPE_AGENT) != 0)
      spin += 400000LL;
    if (spin){
      long long t0 = __builtin_amdgcn_s_memrealtime();
      while (__builtin_amdgcn_s_memrealtime() - t0 < spin) {}
    }
  }
}

extern "C" void kernel_launch(void* const* d_in, const int* in_sizes, int n_in,
                              void* d_out, int out_size, void* d_ws, size_t ws_size,
                              hipStream_t stream){
  (void)in_sizes; (void)n_in; (void)out_size;
  const int*   seq     = (const int*)d_in[0];
  const float* emb     = (const float*)d_in[1];
  const float* w_gate  = (const float*)d_in[2];
  const float* b_gate  = (const float*)d_in[3];
  const float* w_out   = (const float*)d_in[4];
  const float* b_out   = (const float*)d_in[5];
  const float* w_dense = (const float*)d_in[6];
  const float* b_dense = (const float*)d_in[7];
  float* out = (float*)d_out;

  const int NPAD_D = 10112;   // 79 * 128
  char* ws = (char*)d_ws;
  size_t off = 0;
  auto alloc = [&](size_t bytes){ size_t o = off; off += (bytes + 255) & ~(size_t)255; return o; };
  size_t off_W1T = alloc((size_t)2*HID*HID);
  size_t off_UT  = alloc((size_t)2*HID*HID);
  size_t off_WoT = alloc((size_t)2*HID*HID);
  size_t off_WdT = alloc((size_t)2*NPAD_D*HID);
  size_t off_X   = alloc((size_t)2*ROWS*EMB);             // bf16; reused as YS
  size_t off_G0  = alloc((size_t)4*ROWS*HID);
  size_t off_H   = alloc((size_t)2*(ROWS+32)*HID);
  size_t off_ctl = alloc(8192);
  if (ws_size < off) return;

  unsigned short* W1T = (unsigned short*)(ws + off_W1T);
  unsigned short* UT  = (unsigned short*)(ws + off_UT);
  unsigned short* WoT = (unsigned short*)(ws + off_WoT);
  unsigned short* WdT = (unsigned short*)(ws + off_WdT);
  unsigned short* X   = (unsigned short*)(ws + off_X);
  unsigned short* YS  = (unsigned short*)(ws + off_X);
  float*          G0  = (float*)(ws + off_G0);
  unsigned short* Hf  = (unsigned short*)(ws + off_H);
  int*            ctl = (int*)(ws + off_ctl);

  hipMemsetAsync(ctl, 0, 8192, stream);
  hipMemsetAsync(WdT + (size_t)10000*HID, 0, (size_t)2*(NPAD_D-10000)*HID, stream);
  hipMemsetAsync(Hf, 0, (size_t)2*32*HID, stream);

  k_transpose<<<dim3(16,16), 256, 0, stream>>>(w_gate,           W1T, HID, HID);
  k_transpose<<<dim3(16,16), 256, 0, stream>>>(w_gate + HID*HID, UT,  HID, HID);
  k_transpose<<<dim3(16,16), 256, 0, stream>>>(w_out,            WoT, HID, HID);
  k_transpose<<<dim3(157,16),256, 0, stream>>>(w_dense,          WdT, HID, VOCAB);

  k_gather<<<ROWS, 256, 0, stream>>>(seq, emb, X);

  // G0 = X @ W1 + b_gate  (fp32 out)
  k_gemm_bt<false><<<dim3(8,64), 256, 0, stream>>>(X, W1T, b_gate, G0, ROWS, HID, EMB, HID);

  // sequential scan (16 workers elected from 256 candidate blocks)
  k_scan<<<256, 256, 0, stream>>>(UT, G0, Hf, ctl);

  // ys = H @ w_out + b_out  (bf16 out, into X region)
  k_gemm_bt<true><<<dim3(8,64), 256, 0, stream>>>(Hf + (size_t)32*HID, WoT, b_out, YS,
                                                  ROWS, HID, HID, HID);

  // logits = ys @ w_dense + b_dense (fp32 out)
  k_gemm_bt<false><<<dim3(79,64), 256, 0, stream>>>(YS, WdT, b_dense, out,
                                                    ROWS, VOCAB, HID, VOCAB);
}

// Round 10
// 1523.148 us; speedup vs baseline: 3.3597x; 1.6148x over previous
//
#include <hip/hip_runtime.h>
#include <hip/hip_bf16.h>
#include <cstdint>
#include <cstddef>

#define VOCAB 10000
#define EMB   1024
#define HID   1024
#define BATCH 32
#define SEQ   256
#define ROWS  (SEQ*BATCH)   // 8192
#define SNBLK 16            // scan workers; 64 cols each
#define PB    128           // ctrl: published-xcc base (ints)
#define FB    1024          // ctrl: step-flag base; flag[slot][wid] at FB+slot*64+wid*16
#define RST   68            // red stride (floats): >=64 cols + pad; 272B rows (16B-aligned)

typedef __attribute__((ext_vector_type(8))) short short8;
typedef __attribute__((ext_vector_type(4))) float f32x4;

static __device__ __forceinline__ unsigned short f2bf(float f){
  unsigned int u = __builtin_bit_cast(unsigned int, f);
  u += 0x7fffu + ((u >> 16) & 1u);
  return (unsigned short)(u >> 16);
}

// ---------- transpose-convert: fp32 src[K][N] -> bf16 dst[N][K] ----------
__global__ void k_transpose(const float* __restrict__ src, unsigned short* __restrict__ dst,
                            int K, int N){
  __shared__ unsigned short tile[64][65];
  int n0 = blockIdx.x * 64, k0 = blockIdx.y * 64;
  int tid = threadIdx.x;
  #pragma unroll
  for (int it = 0; it < 16; ++it){
    int e = tid + it*256;
    int i = e >> 6, j = e & 63;
    float v = 0.f;
    if (k0 + i < K && n0 + j < N) v = src[(size_t)(k0+i)*N + n0 + j];
    tile[j][i] = f2bf(v);
  }
  __syncthreads();
  #pragma unroll
  for (int it = 0; it < 16; ++it){
    int e = tid + it*256;
    int r = e >> 6, c = e & 63;
    if (n0 + r < N && k0 + c < K)
      dst[(size_t)(n0+r)*K + k0 + c] = tile[r][c];
  }
}

// ---------- embedding gather + fp32->bf16 ----------
__global__ void k_gather(const int* __restrict__ seq, const float* __restrict__ emb,
                         unsigned short* __restrict__ X){
  int r = blockIdx.x;                 // r = t*32 + b
  int t = r >> 5, b = r & 31;
  int idx = seq[b*SEQ + t];
  const float4* s = (const float4*)(emb + (size_t)idx * EMB);
  float4 v = s[threadIdx.x];
  ushort4 o;
  o.x = f2bf(v.x); o.y = f2bf(v.y); o.z = f2bf(v.z); o.w = f2bf(v.w);
  ((ushort4*)(X + (size_t)r * EMB))[threadIdx.x] = o;
}

// ---------- GEMM: C[M][ldc] = A[M][K](bf16) * BT[Npad][K](bf16)^T + bias ----------
template<bool OUT_BF16>
__global__ __launch_bounds__(256) void k_gemm_bt(
    const unsigned short* __restrict__ A,
    const unsigned short* __restrict__ BT,
    const float* __restrict__ bias,
    void* __restrict__ C, int M, int Nreal, int K, int ldc){
  __shared__ __align__(16) unsigned short As[128][40];
  __shared__ __align__(16) unsigned short Bs[128][40];
  int tid  = threadIdx.x;
  int lane = tid & 63, wid = tid >> 6;
  int wr = (wid >> 1) * 64, wc = (wid & 1) * 64;
  int m0 = blockIdx.y * 128, n0 = blockIdx.x * 128;
  int la = lane & 15, ko = (lane >> 4) * 8;
  f32x4 acc[4][4] = {};
  for (int k0 = 0; k0 < K; k0 += 32){
    #pragma unroll
    for (int q = tid; q < 512; q += 256){
      int row = q >> 2, kc = (q & 3) * 8;
      *(uint4*)&As[row][kc] = *(const uint4*)(A  + (size_t)(m0+row)*K + k0 + kc);
      *(uint4*)&Bs[row][kc] = *(const uint4*)(BT + (size_t)(n0+row)*K + k0 + kc);
    }
    __syncthreads();
    short8 av[4], bv[4];
    #pragma unroll
    for (int f = 0; f < 4; ++f){
      av[f] = *(const short8*)&As[wr + f*16 + la][ko];
      bv[f] = *(const short8*)&Bs[wc + f*16 + la][ko];
    }
    #pragma unroll
    for (int mf = 0; mf < 4; ++mf)
      #pragma unroll
      for (int nf = 0; nf < 4; ++nf)
        acc[mf][nf] = __builtin_amdgcn_mfma_f32_16x16x32_bf16(av[mf], bv[nf], acc[mf][nf], 0, 0, 0);
    __syncthreads();
  }
  int dr = (lane >> 4) * 4, dc = lane & 15;
  #pragma unroll
  for (int mf = 0; mf < 4; ++mf){
    #pragma unroll
    for (int nf = 0; nf < 4; ++nf){
      int col = n0 + wc + nf*16 + dc;
      if (col >= Nreal) continue;
      float bb = bias[col];
      #pragma unroll
      for (int rg = 0; rg < 4; ++rg){
        int row = m0 + wr + mf*16 + dr + rg;
        float v = acc[mf][nf][rg] + bb;
        if (OUT_BF16) ((unsigned short*)C)[(size_t)row*ldc + col] = f2bf(v);
        else          ((float*)C)[(size_t)row*ldc + col] = v;
      }
    }
  }
}

// pin 8 short8 values live-in-register (single asm: one waitcnt, no interleave)
#define PIN8(a) asm volatile("" : "+v"((a)[0]),"+v"((a)[1]),"+v"((a)[2]),"+v"((a)[3]), \
                                   "+v"((a)[4]),"+v"((a)[5]),"+v"((a)[6]),"+v"((a)[7]))

// ---------- persistent scan: 16 colocated workers; U in REGISTERS (pinned) ----------
// Wave = K-quarter (256 k) x all 64 cols. Per step: 16 MLP-burst A-loads ->
// pure-MFMA stream (B resident) -> red[4] -> gates. Per-wave flags; wave0 polls.
__global__ __launch_bounds__(256, 1) void k_scan(
    const unsigned short* __restrict__ UT,   // [HID][HID] bf16, UT[n][k]
    const float* __restrict__ G0,            // [ROWS][HID] fp32 (includes b_gate)
    unsigned short* __restrict__ Hfull,      // [(32+ROWS)][HID] bf16, rows 0..31 zeroed
    int* ctrl){
  __shared__ float red[4][32][RST];          // 34 KB
  __shared__ float ldspad[13312];            // 52 KB occupancy limiter: 1 block/CU
  __shared__ int s_slot, s_fast;
  const int tid  = threadIdx.x;
  const int lane = tid & 63, wid = tid >> 6;

  // ---- election (identical to r5-r8: leader-XCD preference + timeout fallback) ----
  if (tid == 0){
    int xcc;
    asm volatile("s_getreg_b32 %0, hwreg(HW_REG_XCC_ID)" : "=s"(xcc));
    xcc &= 0xff;
    int expected = 0;
    __hip_atomic_compare_exchange_strong(&ctrl[0], &expected, xcc + 1,
        __ATOMIC_ACQ_REL, __ATOMIC_ACQUIRE, __HIP_MEMORY_SCOPE_AGENT);
    int lead = (expected == 0) ? xcc : expected - 1;
    int ticket = -1;
    if (xcc == lead){
      ticket = __hip_atomic_fetch_add(&ctrl[32], 1, __ATOMIC_RELAXED, __HIP_MEMORY_SCOPE_AGENT);
    } else {
      for (int it = 0; it < 64; ++it){
        if (__hip_atomic_load(&ctrl[32], __ATOMIC_RELAXED, __HIP_MEMORY_SCOPE_AGENT) >= SNBLK) break;
        for (int j = 0; j < 4; ++j) __builtin_amdgcn_s_sleep(32);
      }
      if (__hip_atomic_load(&ctrl[32], __ATOMIC_RELAXED, __HIP_MEMORY_SCOPE_AGENT) < SNBLK)
        ticket = __hip_atomic_fetch_add(&ctrl[32], 1, __ATOMIC_RELAXED, __HIP_MEMORY_SCOPE_AGENT);
    }
    int slot = (ticket >= 0 && ticket < SNBLK) ? ticket : -1;
    int fast = 1;
    if (slot >= 0){
      __hip_atomic_store(&ctrl[PB + slot], xcc + 1, __ATOMIC_RELEASE, __HIP_MEMORY_SCOPE_AGENT);
      for (int i = 0; i < SNBLK; ++i){
        int v;
        while ((v = __hip_atomic_load(&ctrl[PB + i], __ATOMIC_ACQUIRE, __HIP_MEMORY_SCOPE_AGENT)) == 0)
          __builtin_amdgcn_s_sleep(8);
        if (v - 1 != xcc) fast = 0;
      }
    }
    s_slot = slot; s_fast = fast;
  }
  __syncthreads();
  const int slot = s_slot, fastp = s_fast;
  if (slot == -977) ldspad[tid] = (float)tid;   // keeps pad allocated; never true
  if (slot < 0) return;
  const int n0 = slot * 64;

  const int q  = wid;                  // this wave's K-quarter
  const int la = lane & 15, kg = lane >> 4;
  const int b  = tid >> 3, nn = (tid & 7) * 8;

  // ---- B preload ONCE: U^T fragments, 32 x short8 = 128 VGPR, resident all 256 steps ----
  short8 Br[4][8];                     // [col-group][kc]
  #pragma unroll
  for (int cg = 0; cg < 4; ++cg)
    #pragma unroll
    for (int kc = 0; kc < 8; ++kc)
      Br[cg][kc] = *(const short8*)(UT + (size_t)(n0 + cg*16 + la)*HID + q*256 + kc*32 + kg*8);

  float creg[8];
  #pragma unroll
  for (int j = 0; j < 8; ++j) creg[j] = 0.f;
  float g0r[8];
  {
    const float* gp = G0 + (size_t)b * HID + n0 + nn;
    float4 lo = *(const float4*)gp, hi = *(const float4*)(gp + 4);
    g0r[0]=lo.x; g0r[1]=lo.y; g0r[2]=lo.z; g0r[3]=lo.w;
    g0r[4]=hi.x; g0r[5]=hi.y; g0r[6]=hi.z; g0r[7]=hi.w;
  }

  for (int t = 0; t < SEQ; ++t){
    // ---- pin B resident (forbids remat/spill of the 128 B-VGPRs this iteration) ----
    PIN8(Br[0]); PIN8(Br[1]); PIN8(Br[2]); PIN8(Br[3]);

    // ---- wait for peers' h_{t-1}: wave0 polls 64 flags; others park at barrier ----
    if (t > 0){
      if (wid == 0){
        const int* fp = &ctrl[FB + (lane & 15)*64 + (lane >> 4)*16];
        int guard = 0, dead = 0;
        for (;;){
          int v = __hip_atomic_load(fp, __ATOMIC_RELAXED, __HIP_MEMORY_SCOPE_AGENT);
          if (__all(v >= t)) break;
          if (++guard > (1<<15)) { dead = 1; break; }
        }
        if (dead && lane == 0)
          __hip_atomic_fetch_or(&ctrl[64], 1, __ATOMIC_RELAXED, __HIP_MEMORY_SCOPE_AGENT);
        if (!fastp) __threadfence();       // slow path: inv before remote h-reads
      }
      __syncthreads();                     // also orders gates-reads(t-1) vs red-writes(t)
    }

    // ---- A-loads: 16 b128 in one MLP burst, then ONE pin (single waitcnt) ----
    const unsigned short* hpA = Hfull + (size_t)t*32*HID + (size_t)la*HID + q*256 + kg*8;
    const unsigned short* hpB = hpA + (size_t)16*HID;
    short8 A0[8], A1[8];
    #pragma unroll
    for (int kc = 0; kc < 8; ++kc){
      A0[kc] = *(const short8*)(hpA + kc*32);
      A1[kc] = *(const short8*)(hpB + kc*32);
    }
    asm volatile("" : "+v"(A0[0]),"+v"(A0[1]),"+v"(A0[2]),"+v"(A0[3]),
                      "+v"(A0[4]),"+v"(A0[5]),"+v"(A0[6]),"+v"(A0[7]),
                      "+v"(A1[0]),"+v"(A1[1]),"+v"(A1[2]),"+v"(A1[3]),
                      "+v"(A1[4]),"+v"(A1[5]),"+v"(A1[6]),"+v"(A1[7]));

    // ---- G0 prefetch for next step: issued now, completes under MFMA+gates ----
    float4 gnlo, gnhi;
    {
      int tn = (t + 1 < SEQ) ? (t + 1) : t;
      const float* gp = G0 + ((size_t)tn*32 + b) * HID + n0 + nn;
      gnlo = *(const float4*)gp; gnhi = *(const float4*)(gp + 4);
    }

    // ---- pure-register MFMA stream: 64 MFMA, no memory ops ----
    f32x4 acc0[4] = {}, acc1[4] = {};
    #pragma unroll
    for (int kc = 0; kc < 8; ++kc)
      #pragma unroll
      for (int cg = 0; cg < 4; ++cg){
        acc0[cg] = __builtin_amdgcn_mfma_f32_16x16x32_bf16(A0[kc], Br[cg][kc], acc0[cg], 0, 0, 0);
        acc1[cg] = __builtin_amdgcn_mfma_f32_16x16x32_bf16(A1[kc], Br[cg][kc], acc1[cg], 0, 0, 0);
      }

    // ---- K-quarter partials -> red ----
    #pragma unroll
    for (int cg = 0; cg < 4; ++cg)
      #pragma unroll
      for (int rg = 0; rg < 4; ++rg){
        red[q][kg*4 + rg][cg*16 + la]      = acc0[cg][rg];
        red[q][16 + kg*4 + rg][cg*16 + la] = acc1[cg][rg];
      }
    __syncthreads();

    // ---- gates: 4-quarter sum + fast sigmoid/tanh; h-write ----
    float4 q0lo = *(const float4*)&red[0][b][nn], q0hi = *(const float4*)&red[0][b][nn+4];
    float4 q1lo = *(const float4*)&red[1][b][nn], q1hi = *(const float4*)&red[1][b][nn+4];
    float4 q2lo = *(const float4*)&red[2][b][nn], q2hi = *(const float4*)&red[2][b][nn+4];
    float4 q3lo = *(const float4*)&red[3][b][nn], q3hi = *(const float4*)&red[3][b][nn+4];
    float gg[8] = {
      q0lo.x+q1lo.x+q2lo.x+q3lo.x+g0r[0], q0lo.y+q1lo.y+q2lo.y+q3lo.y+g0r[1],
      q0lo.z+q1lo.z+q2lo.z+q3lo.z+g0r[2], q0lo.w+q1lo.w+q2lo.w+q3lo.w+g0r[3],
      q0hi.x+q1hi.x+q2hi.x+q3hi.x+g0r[4], q0hi.y+q1hi.y+q2hi.y+q3hi.y+g0r[5],
      q0hi.z+q1hi.z+q2hi.z+q3hi.z+g0r[6], q0hi.w+q1hi.w+q2hi.w+q3hi.w+g0r[7] };
    short8 hv;
    #pragma unroll
    for (int j = 0; j < 8; ++j){
      float g  = gg[j];
      float e  = __expf(-g);
      float s  = __builtin_amdgcn_rcpf(1.f + e);
      float e2 = e * e;
      float tg = 2.f * __builtin_amdgcn_rcpf(1.f + e2) - 1.f;
      float cn = s * (creg[j] + tg);
      creg[j] = cn;
      float ec = __expf(-2.f * cn);
      float th = 2.f * __builtin_amdgcn_rcpf(1.f + ec) - 1.f;
      hv[j] = (short)f2bf(th * s);
    }
    *(short8*)(Hfull + ((size_t)(t+1)*32 + b) * HID + n0 + nn) = hv;

    // ---- per-wave flag after own h-stores drained ----
    asm volatile("s_waitcnt vmcnt(0)" ::: "memory");
    if (!fastp) __threadfence();
    if (lane == 0)
      __hip_atomic_store(&ctrl[FB + slot*64 + wid*16], t + 1,
                         __ATOMIC_RELAXED, __HIP_MEMORY_SCOPE_AGENT);

    g0r[0]=gnlo.x; g0r[1]=gnlo.y; g0r[2]=gnlo.z; g0r[3]=gnlo.w;
    g0r[4]=gnhi.x; g0r[5]=gnhi.y; g0r[6]=gnhi.z; g0r[7]=gnhi.w;
  }

  // telemetry: slow path +1ms, any deadman +4ms (visible in dur_us)
  if (slot == 0 && tid == 0){
    long long spin = 0;
    if (!fastp) spin += 100000LL;
    if (__hip_atomic_load(&ctrl[64], __ATOMIC_RELAXED, __HIP_MEMORY_SCOPE_AGENT) != 0)
      spin += 400000LL;
    if (spin){
      long long t0 = __builtin_amdgcn_s_memrealtime();
      while (__builtin_amdgcn_s_memrealtime() - t0 < spin) {}
    }
  }
}

extern "C" void kernel_launch(void* const* d_in, const int* in_sizes, int n_in,
                              void* d_out, int out_size, void* d_ws, size_t ws_size,
                              hipStream_t stream){
  (void)in_sizes; (void)n_in; (void)out_size;
  const int*   seq     = (const int*)d_in[0];
  const float* emb     = (const float*)d_in[1];
  const float* w_gate  = (const float*)d_in[2];
  const float* b_gate  = (const float*)d_in[3];
  const float* w_out   = (const float*)d_in[4];
  const float* b_out   = (const float*)d_in[5];
  const float* w_dense = (const float*)d_in[6];
  const float* b_dense = (const float*)d_in[7];
  float* out = (float*)d_out;

  const int NPAD_D = 10112;   // 79 * 128
  char* ws = (char*)d_ws;
  size_t off = 0;
  auto alloc = [&](size_t bytes){ size_t o = off; off += (bytes + 255) & ~(size_t)255; return o; };
  size_t off_W1T = alloc((size_t)2*HID*HID);
  size_t off_UT  = alloc((size_t)2*HID*HID);
  size_t off_WoT = alloc((size_t)2*HID*HID);
  size_t off_WdT = alloc((size_t)2*NPAD_D*HID);
  size_t off_X   = alloc((size_t)2*ROWS*EMB);             // bf16; reused as YS
  size_t off_G0  = alloc((size_t)4*ROWS*HID);
  size_t off_H   = alloc((size_t)2*(ROWS+32)*HID);
  size_t off_ctl = alloc(8192);
  if (ws_size < off) return;

  unsigned short* W1T = (unsigned short*)(ws + off_W1T);
  unsigned short* UT  = (unsigned short*)(ws + off_UT);
  unsigned short* WoT = (unsigned short*)(ws + off_WoT);
  unsigned short* WdT = (unsigned short*)(ws + off_WdT);
  unsigned short* X   = (unsigned short*)(ws + off_X);
  unsigned short* YS  = (unsigned short*)(ws + off_X);
  float*          G0  = (float*)(ws + off_G0);
  unsigned short* Hf  = (unsigned short*)(ws + off_H);
  int*            ctl = (int*)(ws + off_ctl);

  hipMemsetAsync(ctl, 0, 8192, stream);
  hipMemsetAsync(WdT + (size_t)10000*HID, 0, (size_t)2*(NPAD_D-10000)*HID, stream);
  hipMemsetAsync(Hf, 0, (size_t)2*32*HID, stream);

  k_transpose<<<dim3(16,16), 256, 0, stream>>>(w_gate,           W1T, HID, HID);
  k_transpose<<<dim3(16,16), 256, 0, stream>>>(w_gate + HID*HID, UT,  HID, HID);
  k_transpose<<<dim3(16,16), 256, 0, stream>>>(w_out,            WoT, HID, HID);
  k_transpose<<<dim3(157,16),256, 0, stream>>>(w_dense,          WdT, HID, VOCAB);

  k_gather<<<ROWS, 256, 0, stream>>>(seq, emb, X);

  // G0 = X @ W1 + b_gate  (fp32 out)
  k_gemm_bt<false><<<dim3(8,64), 256, 0, stream>>>(X, W1T, b_gate, G0, ROWS, HID, EMB, HID);

  // sequential scan (16 workers elected from 256 candidate blocks)
  k_scan<<<256, 256, 0, stream>>>(UT, G0, Hf, ctl);

  // ys = H @ w_out + b_out  (bf16 out, into X region)
  k_gemm_bt<true><<<dim3(8,64), 256, 0, stream>>>(Hf + (size_t)32*HID, WoT, b_out, YS,
                                                  ROWS, HID, HID, HID);

  // logits = ys @ w_dense + b_dense (fp32 out)
  k_gemm_bt<false><<<dim3(79,64), 256, 0, stream>>>(YS, WdT, b_dense, out,
                                                    ROWS, VOCAB, HID, VOCAB);
}